// Round 15
// baseline (108.159 us; speedup 1.0000x reference)
//
#include <hip/hip_runtime.h>

// CostVolume via banded-correlation MFMA (v_mfma_f32_16x16x32_f16).
// cost[b,h,w,(sh+4)*9+(sw+4)] = LeakyReLU_0.1( mean_c x1[b,h,w,c]*warped[b,h+sh,w+sw,c] )
// B=8 H=128 W=192 C=128, MD=4. Output fp32 [B,H,W,81].
//
// Round-15: TWO-TILE PIPELINED BLOCKS (grid 768), R11 dual-set schedule
// continued across the tile boundary. Attacks the measured ~40% of block
// lifetime with zero loads in flight (steps 2-3 + epilogue + next block's
// cold prologue): tile1's chunks c0..c2 are issued during tile0's steps
// 1..3 (parked in the SAME gpA/gpB sets), committed only after tile0's
// store burst. Half the cold prologues disappear; HBM stays busy through
// tile0's tail.
// R10's failure modes fixed:
//  - STRIDE-interleaved tiles (block kb -> tiles {base, base+96} of its
//    XCD image, base = kb>>3): co-resident blocks have CONSECUTIVE base ->
//    halo-sharing neighbor tiles run concurrently -> halo stays L2-hit
//    (R10 chunked 3-per-block, neighbors never co-resident, FETCH +140MB).
//  - Store burst stays tight and uninterrupted: next-tile loads are parked
//    in regs across it; LDS commits happen after the next barrier.
// R14 lesson: LDS bank conflicts are NOT on the critical path (pad raised
// conflicts 4.4M->5.6M, time flat) -> pad reverted, KQB=384.
// Kept: lb(512,4) (lb3 = 21.6% occupancy cliff), fmaxf LeakyReLU, XCD
// mapping, swizzled conflict-free staging, lgkm-only barriers, rolling x1,
// direct band stores.
//
// Schedule (8 global steps, buffers alternate by step parity):
//  prologue: OFFS(t0); LOADA(c0); LOADB(c1); x1; WRITEA->b0; LOADA(c2)
//  p0s0: bar; WRITEB->b1[c1]; LOADB(c3);            mfma b0
//  p0s1: bar; WRITEA->b0[c2]; OFFS(t1); LOADA(t1c0); mfma b1
//  p0s2: bar; WRITEB->b1[c3]; LOADB(t1c1);          mfma b0
//  p0s3: bar; WRITEA->b0[t1c0]; LOADA(t1c2);        mfma b1
//  epilogue(t0): tight store burst (t1c1/c2 in flight); zero acc
//  p1s0: bar; WRITEB->b1[t1c1]; LOADB(t1c3);        mfma b0
//  p1s1: bar; WRITEA->b0[t1c2];                     mfma b1
//  p1s2: bar; WRITEB->b1[t1c3];                     mfma b0
//  p1s3: bar;                                       mfma b1
//  epilogue(t1)

namespace {
constexpr int Bb = 8, Hh = 128, Ww = 192, Cn = 128;
constexpr int MDc = 4;
constexpr int TH = 8, TWT = 16;        // block tile: 8 rows x 16 px
constexpr int NTHR = 512;              // 8 waves
constexpr int RH = 16;                 // staged warped rows  (h0-4 .. h0+11)
constexpr int RPX = 24;                // staged warped px    (w0-4 .. w0+19)
constexpr int KC = 32;                 // channels per chunk
constexpr int NCH = Cn / KC;           // 4
constexpr int KQB = RPX * 16;          // 384 B per kq-plane (24 x 16B slots)
constexpr int ROWB = 4 * KQB;          // 1536 B per staged row
constexpr int BUFB = RH * ROWB;        // 24576 B per buffer
constexpr int RUNS = RH * RPX * 4;     // 1536 8-channel runs per chunk
constexpr int NIT = RUNS / NTHR;       // 3
constexpr float NEG = 0.1f;
}

typedef __fp16 h2v   __attribute__((ext_vector_type(2)));
typedef __fp16 f16x8 __attribute__((ext_vector_type(8)));
typedef float  f32x4 __attribute__((ext_vector_type(4)));

__device__ __forceinline__ unsigned pkh2(float a, float b) {
    h2v h = __builtin_amdgcn_cvt_pkrtz(a, b);
    return __builtin_bit_cast(unsigned, h);
}

// Barrier with LDS-only drain: global prefetch loads stay in flight across it.
__device__ __forceinline__ void barrier_lgkm() {
    asm volatile("s_waitcnt lgkmcnt(0)\n\ts_barrier" ::: "memory");
}

__global__ __launch_bounds__(NTHR, 4)
void costvol_mfma(const float* __restrict__ x1,
                  const float* __restrict__ wp,
                  float* __restrict__ out)
{
    __shared__ __align__(16) unsigned char smem[2 * BUFB];   // 48 KiB

    const int tid  = threadIdx.x;
    const int wv   = tid >> 6;        // 0..7 : h-row within stripe
    const int lane = tid & 63;
    const int nI   = lane & 15;       // A-row m / B-col n lane index
    const int kq   = lane >> 4;       // 0..3 : k-group (8 channels each)

    // 768 blocks = 8 XCDs x 96; block kb -> XCD kb&7, tiles {base, base+96}
    // of that XCD's 192-tile image. Consecutive kb -> consecutive base, so
    // halo-sharing neighbor tiles are co-resident (L2 hits preserved).
    const int kb   = blockIdx.x;
    const int xcd  = kb & 7;
    const int base = kb >> 3;         // 0..95
    const int wg0  = xcd * 192 + base;

    int w0, h0, b0_;                  // current tile (epilogue uses these)
    {
        int bx = wg0 % 12, t2 = wg0 / 12;
        w0 = bx * TWT; h0 = (t2 & 15) * TH; b0_ = t2 >> 4;
    }
    int w1 = 0, h1 = 0, b1_ = 0;      // next tile (decoded at p0s1)

    // LDS offsets are tile-independent
    int l_off[NIT];
#pragma unroll
    for (int it = 0; it < NIT; ++it) {
        int s = tid + it * NTHR, skq = s & 3, t = s >> 2;
        int px = t % RPX, row = t / RPX;
        l_off[it] = row * ROWB + skq * KQB + ((px ^ (skq << 1)) * 16);
    }

    int g_off[NIT]; bool g_ok[NIT];
    auto OFFS = [&](int tw0, int th0, int tb) {
#pragma unroll
        for (int it = 0; it < NIT; ++it) {
            int s = tid + it * NTHR, skq = s & 3, t = s >> 2;
            int px = t % RPX, row = t / RPX;
            int hw = th0 - MDc + row, ww = tw0 - MDc + px;
            bool ok = (unsigned)hw < (unsigned)Hh && (unsigned)ww < (unsigned)Ww;
            g_ok[it]  = ok;
            g_off[it] = ((tb * Hh + (ok ? hw : 0)) * Ww + (ok ? ww : 0)) * Cn + skq * 8;
        }
    };
    OFFS(w0, h0, b0_);

    // Two independent staging register sets: A and B alternate chunks.
    uint4 gpA[NIT], gpB[NIT];
    auto LOADA = [&](int ch) {
#pragma unroll
        for (int it = 0; it < NIT; ++it) {
            if (g_ok[it]) {
                const float* p = wp + g_off[it] + ch * KC;
                float4 u = *reinterpret_cast<const float4*>(p);
                float4 v = *reinterpret_cast<const float4*>(p + 4);
                gpA[it] = make_uint4(pkh2(u.x, u.y), pkh2(u.z, u.w),
                                     pkh2(v.x, v.y), pkh2(v.z, v.w));
            } else {
                gpA[it] = make_uint4(0u, 0u, 0u, 0u);
            }
        }
    };
    auto LOADB = [&](int ch) {
#pragma unroll
        for (int it = 0; it < NIT; ++it) {
            if (g_ok[it]) {
                const float* p = wp + g_off[it] + ch * KC;
                float4 u = *reinterpret_cast<const float4*>(p);
                float4 v = *reinterpret_cast<const float4*>(p + 4);
                gpB[it] = make_uint4(pkh2(u.x, u.y), pkh2(u.z, u.w),
                                     pkh2(v.x, v.y), pkh2(v.z, v.w));
            } else {
                gpB[it] = make_uint4(0u, 0u, 0u, 0u);
            }
        }
    };
    auto WRITEA = [&](int buf) {
#pragma unroll
        for (int it = 0; it < NIT; ++it)
            *reinterpret_cast<uint4*>(smem + buf * BUFB + l_off[it]) = gpA[it];
    };
    auto WRITEB = [&](int buf) {
#pragma unroll
        for (int it = 0; it < NIT; ++it)
            *reinterpret_cast<uint4*>(smem + buf * BUFB + l_off[it]) = gpB[it];
    };

    // ---- prologue (tile0 cold start; the only one) ----
    LOADA(0);
    LOADB(1);

    const float* xp  = x1 + ((size_t)((b0_ * Hh + h0 + wv) * Ww) + w0 + nI) * Cn + kq * 8;
    const float* xp2 = xp;             // switched at p0s1
    float4 ar_u = *reinterpret_cast<const float4*>(xp);
    float4 ar_v = *reinterpret_cast<const float4*>(xp + 4);

    f32x4 ac0[9], ac1[9];
#pragma unroll
    for (int s = 0; s < 9; ++s) {
        f32x4 z = {0.f, 0.f, 0.f, 0.f};
        ac0[s] = z; ac1[s] = z;
    }

    // per-lane B fragment offset within a staged row; tile1 = ro0 + 128
    const int ro0 = kq * KQB + ((nI ^ (kq << 1)) * 16);

    WRITEA(0);       // commit c0 -> buf0
    LOADA(2);        // c2 in flight across p0s0..p0s1

    const float sc = 1.0f / (float)Cn;

#pragma unroll
    for (int pass = 0; pass < 2; ++pass) {
#pragma unroll
        for (int ch = 0; ch < NCH; ++ch) {
            barrier_lgkm();
            if (pass == 0) {
                if (ch == 0) { WRITEB(1); LOADB(3); }          // c1->b1; c3 issue
                if (ch == 1) {
                    WRITEA(0);                                  // c2->b0
                    int wg1 = wg0 + 96;                         // next tile
                    int bx = wg1 % 12, t2 = wg1 / 12;
                    w1 = bx * TWT; h1 = (t2 & 15) * TH; b1_ = t2 >> 4;
                    OFFS(w1, h1, b1_);
                    xp2 = x1 + ((size_t)((b1_ * Hh + h1 + wv) * Ww) + w1 + nI) * Cn + kq * 8;
                    LOADA(0);                                   // t1c0 issue
                }
                if (ch == 2) { WRITEB(1); LOADB(1); }          // c3->b1; t1c1 issue
                if (ch == 3) { WRITEA(0); LOADA(2); }          // t1c0->b0; t1c2 issue
            } else {
                if (ch == 0) { WRITEB(1); LOADB(3); }          // t1c1->b1; t1c3 issue
                if (ch == 1) { WRITEA(0); }                    // t1c2->b0
                if (ch == 2) { WRITEB(1); }                    // t1c3->b1
            }
            // x1: convert this step's chunk, refill for the next step
            uint4 afr = make_uint4(pkh2(ar_u.x, ar_u.y), pkh2(ar_u.z, ar_u.w),
                                   pkh2(ar_v.x, ar_v.y), pkh2(ar_v.z, ar_v.w));
            if (pass == 0) {
                if (ch < 3) {
                    ar_u = *reinterpret_cast<const float4*>(xp + (ch + 1) * KC);
                    ar_v = *reinterpret_cast<const float4*>(xp + (ch + 1) * KC + 4);
                } else {
                    ar_u = *reinterpret_cast<const float4*>(xp2);
                    ar_v = *reinterpret_cast<const float4*>(xp2 + 4);
                }
            } else if (ch < 3) {
                ar_u = *reinterpret_cast<const float4*>(xp2 + (ch + 1) * KC);
                ar_v = *reinterpret_cast<const float4*>(xp2 + (ch + 1) * KC + 4);
            }
            f16x8 av = __builtin_bit_cast(f16x8, afr);
            const unsigned char* bse = smem + (ch & 1) * BUFB;
#pragma unroll
            for (int sh = 0; sh < 9; ++sh) {
                const unsigned char* rp = bse + (wv + sh) * ROWB;
                uint4 b0 = *reinterpret_cast<const uint4*>(rp + ro0);
                uint4 b1 = *reinterpret_cast<const uint4*>(rp + ro0 + 128);
                ac0[sh] = __builtin_amdgcn_mfma_f32_16x16x32_f16(
                    av, __builtin_bit_cast(f16x8, b0), ac0[sh], 0, 0, 0);
                ac1[sh] = __builtin_amdgcn_mfma_f32_16x16x32_f16(
                    av, __builtin_bit_cast(f16x8, b1), ac1[sh], 0, 0, 0);
            }
        }

        // ---- epilogue for the current tile: tight, uninterrupted store
        //      burst (next-tile loads are parked in regs, committed later).
        //      C/D map: col=n=lane&15, row=m=(lane>>4)*4+reg.
        //      tile0: p=nI   -> sw4=nI-m,   valid d in [0,8]
        //      tile1: p=nI+8 -> sw4=nI-m+8, valid d in [-8,0] && nI>=8
        const size_t rowbase = ((size_t)((b0_ * Hh + h0 + wv) * Ww) + w0) * 81;
#pragma unroll
        for (int rg = 0; rg < 4; ++rg) {
            int m = kq * 4 + rg;
            int d = nI - m;
            bool t0 = (d >= 0 && d <= 8);
            bool t1 = (d >= -8 && d <= 0 && nI >= 8);
            size_t mb = rowbase + (size_t)m * 81;
#pragma unroll
            for (int sh = 0; sh < 9; ++sh) {
                if (t0) {
                    float v = ac0[sh][rg] * sc;
                    out[mb + sh * 9 + d] = fmaxf(v, NEG * v);
                }
                if (t1) {
                    float v = ac1[sh][rg] * sc;
                    out[mb + sh * 9 + d + 8] = fmaxf(v, NEG * v);
                }
            }
        }

        if (pass == 0) {
#pragma unroll
            for (int s = 0; s < 9; ++s) {
                f32x4 z = {0.f, 0.f, 0.f, 0.f};
                ac0[s] = z; ac1[s] = z;
            }
            w0 = w1; h0 = h1; b0_ = b1_;   // tile1 becomes current
        }
    }
}

extern "C" void kernel_launch(void* const* d_in, const int* in_sizes, int n_in,
                              void* d_out, int out_size, void* d_ws, size_t ws_size,
                              hipStream_t stream) {
    const float* x1 = (const float*)d_in[0];
    const float* wp = (const float*)d_in[1];
    float* out = (float*)d_out;
    dim3 grid(768, 1, 1);   // 8 XCDs x 96 blocks x 2 stride-interleaved tiles
    costvol_mfma<<<grid, NTHR, 0, stream>>>(x1, wp, out);
}

// Round 16
// 61.864 us; speedup vs baseline: 1.7483x; 1.7483x over previous
//
#include <hip/hip_runtime.h>

// CostVolume via banded-correlation MFMA (v_mfma_f32_16x16x32_f16).
// cost[b,h,w,(sh+4)*9+(sw+4)] = LeakyReLU_0.1( mean_c x1[b,h,w,c]*warped[b,h+sh,w+sw,c] )
// B=8 H=128 W=192 C=128, MD=4. Output fp32 [B,H,W,81].
//
// FINAL (round-16 consolidation) = R11 champion (55.3us) + fmaxf LeakyReLU.
// Session ledger 87.2 -> 55.3us; every alternative measured and closed:
//  - direct band stores replace LDS epilogue (R3, -10us; WRITE == ideal)
//  - rolling x1 prefetch + ro0+128 fold (R4, -18us)
//  - dual-set depth-2 staging prefetch (R11, -4.4us; the validated MLP
//    lever -- two 49KB bursts in flight, load->commit >= 1.5-2 steps)
//  - occupancy levers DEAD (R5/R8: ~40% pin is a consequence of block
//    wall time, not a resource cap; reg/LDS budgets don't move it)
//  - depth-3 parking DEAD (R12: allocator pins arch VGPR at 64, sinks
//    the schedule back)
//  - LDS bank conflicts NOT critical-path (R14: +27% conflicts, flat time)
//  - multi-tile blocks DEAD x2 (R10/R15: band-store line merging requires
//    single-tile temporally-compact store bursts; FETCH/WRITE balloon)
//  - operand flip DEAD (R7), halo amplification DEAD (R1/R5), setprio
//    hurts lockstep waves (R13), lgkm-vs-full barrier neutral (R2)
//  - lb(512,4) LOAD-BEARING: lb(,3) builds collapse to 21.6% occupancy
// Remaining gap to the 27us HBM floor is the phase-serialized decomposition
// itself (64 arch + 72 AGPR shape -> ~1.6 resident blocks, ~50% HBM duty);
// beating it requires a different register-shape design, not perturbation.
//
// Structure: 8x16 tile, 8 waves (wave = one h-row, all 81 shifts).
// Warped staged in LDS [row][kq][px ^ (kq<<1)] 16B slots (conflict-free
// staging writes and B-fragment reads); x1 in registers; K-chunks of 32,
// double-buffered; XCD swizzle (192 wg = one image per XCD); direct band
// stores (36B runs merge to full lines in L2).

namespace {
constexpr int Bb = 8, Hh = 128, Ww = 192, Cn = 128;
constexpr int MDc = 4;
constexpr int TH = 8, TWT = 16;        // block tile: 8 rows x 16 px
constexpr int NTHR = 512;              // 8 waves
constexpr int RH = 16;                 // staged warped rows  (h0-4 .. h0+11)
constexpr int RPX = 24;                // staged warped px    (w0-4 .. w0+19)
constexpr int KC = 32;                 // channels per chunk
constexpr int NCH = Cn / KC;           // 4
constexpr int KQB = RPX * 16;          // 384 B per kq-plane (24 x 16B slots)
constexpr int ROWB = 4 * KQB;          // 1536 B per staged row
constexpr int BUFB = RH * ROWB;        // 24576 B per buffer
constexpr int RUNS = RH * RPX * 4;     // 1536 8-channel runs per chunk
constexpr int NIT = RUNS / NTHR;       // 3
constexpr float NEG = 0.1f;
}

typedef __fp16 h2v   __attribute__((ext_vector_type(2)));
typedef __fp16 f16x8 __attribute__((ext_vector_type(8)));
typedef float  f32x4 __attribute__((ext_vector_type(4)));

__device__ __forceinline__ unsigned pkh2(float a, float b) {
    h2v h = __builtin_amdgcn_cvt_pkrtz(a, b);
    return __builtin_bit_cast(unsigned, h);
}

// Barrier with LDS-only drain: global prefetch loads stay in flight across it.
__device__ __forceinline__ void barrier_lgkm() {
    asm volatile("s_waitcnt lgkmcnt(0)\n\ts_barrier" ::: "memory");
}

__global__ __launch_bounds__(NTHR, 4)
void costvol_mfma(const float* __restrict__ x1,
                  const float* __restrict__ wp,
                  float* __restrict__ out)
{
    __shared__ __align__(16) unsigned char smem[2 * BUFB];   // 48 KiB

    const int tid  = threadIdx.x;
    const int wv   = tid >> 6;        // 0..7 : h-row within stripe
    const int lane = tid & 63;
    const int nI   = lane & 15;       // A-row m / B-col n lane index
    const int kq   = lane >> 4;       // 0..3 : k-group (8 channels each)

    // XCD swizzle: 1536 wg = 8 XCDs x 192; 192 = one batch image (12x16).
    const int id = blockIdx.x;
    const int wg = (id & 7) * 192 + (id >> 3);
    const int bx = wg % 12;
    const int t2 = wg / 12;
    const int by = t2 & 15;
    const int bz = t2 >> 4;

    const int w0 = bx * TWT;
    const int h0 = by * TH;
    const int b  = bz;

    // ---- warped staging decode: run = (row, px, kq), kq innermost ----
    int g_off[NIT]; int l_off[NIT]; bool g_ok[NIT];
#pragma unroll
    for (int it = 0; it < NIT; ++it) {
        int s   = tid + it * NTHR;    // 0..1535
        int skq = s & 3;
        int t   = s >> 2;             // 0..383
        int px  = t % RPX;
        int row = t / RPX;
        int hw  = h0 - MDc + row;
        int ww  = w0 - MDc + px;
        bool ok = (unsigned)hw < (unsigned)Hh && (unsigned)ww < (unsigned)Ww;
        g_ok[it]  = ok;
        g_off[it] = ((b * Hh + (ok ? hw : 0)) * Ww + (ok ? ww : 0)) * Cn + skq * 8;
        l_off[it] = row * ROWB + skq * KQB + ((px ^ (skq << 1)) * 16);
    }

    // Two independent staging register sets: A = even chunks, B = odd.
    uint4 gpA[NIT], gpB[NIT];
    auto LOADA = [&](int ch) {
#pragma unroll
        for (int it = 0; it < NIT; ++it) {
            if (g_ok[it]) {
                const float* p = wp + g_off[it] + ch * KC;
                float4 u = *reinterpret_cast<const float4*>(p);
                float4 v = *reinterpret_cast<const float4*>(p + 4);
                gpA[it] = make_uint4(pkh2(u.x, u.y), pkh2(u.z, u.w),
                                     pkh2(v.x, v.y), pkh2(v.z, v.w));
            } else {
                gpA[it] = make_uint4(0u, 0u, 0u, 0u);
            }
        }
    };
    auto LOADB = [&](int ch) {
#pragma unroll
        for (int it = 0; it < NIT; ++it) {
            if (g_ok[it]) {
                const float* p = wp + g_off[it] + ch * KC;
                float4 u = *reinterpret_cast<const float4*>(p);
                float4 v = *reinterpret_cast<const float4*>(p + 4);
                gpB[it] = make_uint4(pkh2(u.x, u.y), pkh2(u.z, u.w),
                                     pkh2(v.x, v.y), pkh2(v.z, v.w));
            } else {
                gpB[it] = make_uint4(0u, 0u, 0u, 0u);
            }
        }
    };
    auto WRITEA = [&](int buf) {
#pragma unroll
        for (int it = 0; it < NIT; ++it)
            *reinterpret_cast<uint4*>(smem + buf * BUFB + l_off[it]) = gpA[it];
    };
    auto WRITEB = [&](int buf) {
#pragma unroll
        for (int it = 0; it < NIT; ++it)
            *reinterpret_cast<uint4*>(smem + buf * BUFB + l_off[it]) = gpB[it];
    };

    // ---- prologue: issue c0,c1 back-to-back, then x1, commit c0, issue c2.
    LOADA(0);
    LOADB(1);

    const float* xp = x1 + ((size_t)((b * Hh + h0 + wv) * Ww) + w0 + nI) * Cn + kq * 8;
    float4 ar_u = *reinterpret_cast<const float4*>(xp);
    float4 ar_v = *reinterpret_cast<const float4*>(xp + 4);

    f32x4 ac0[9], ac1[9];
#pragma unroll
    for (int s = 0; s < 9; ++s) {
        f32x4 z = {0.f, 0.f, 0.f, 0.f};
        ac0[s] = z; ac1[s] = z;
    }

    // per-lane B fragment offset within a staged row; tile1 = ro0 + 128
    // (identity: ((nI+8)^(kq<<1))*16 == (nI^(kq<<1))*16 + 128)
    const int ro0 = kq * KQB + ((nI ^ (kq << 1)) * 16);

    WRITEA(0);       // commit c0 -> buf0 (waits only on gpA's loads)
    LOADA(2);        // c2 in flight across steps 0..1

    int cur = 0;
#pragma unroll
    for (int ch = 0; ch < NCH; ++ch) {
        barrier_lgkm();
        // commit chunk ch+1 into the other buffer; issue chunk ch+3
        if (ch == 0) { WRITEB(1); LOADB(3); }   // c1 -> buf1; c3 spans steps 0..2
        if (ch == 1) { WRITEA(0); }             // c2 -> buf0
        if (ch == 2) { WRITEB(1); }             // c3 -> buf1
        // x1: convert this chunk (loaded last step), issue next chunk
        uint4 afr = make_uint4(pkh2(ar_u.x, ar_u.y), pkh2(ar_u.z, ar_u.w),
                               pkh2(ar_v.x, ar_v.y), pkh2(ar_v.z, ar_v.w));
        if (ch + 1 < NCH) {
            ar_u = *reinterpret_cast<const float4*>(xp + (ch + 1) * KC);
            ar_v = *reinterpret_cast<const float4*>(xp + (ch + 1) * KC + 4);
        }
        f16x8 av = __builtin_bit_cast(f16x8, afr);
        const unsigned char* base = smem + cur * BUFB;
#pragma unroll
        for (int sh = 0; sh < 9; ++sh) {
            const unsigned char* rp = base + (wv + sh) * ROWB;   // staged row ly+sh
            uint4 b0 = *reinterpret_cast<const uint4*>(rp + ro0);
            uint4 b1 = *reinterpret_cast<const uint4*>(rp + ro0 + 128);
            ac0[sh] = __builtin_amdgcn_mfma_f32_16x16x32_f16(
                av, __builtin_bit_cast(f16x8, b0), ac0[sh], 0, 0, 0);
            ac1[sh] = __builtin_amdgcn_mfma_f32_16x16x32_f16(
                av, __builtin_bit_cast(f16x8, b1), ac1[sh], 0, 0, 0);
        }
        cur ^= 1;
    }

    // ---- direct band stores: no LDS round-trip, no barriers ----
    // C/D map: col=n=lane&15, row=m=(lane>>4)*4+reg
    // tile0: staged px p = nI      -> (m, sw4 = nI-m),   valid d=nI-m in [0,8]
    // tile1: staged px p = nI + 8  -> (m, sw4 = nI-m+8), valid d in [-8,0] && nI>=8
    // out k-index = sh*9 + sw4. Active lanes per (rg,sh,tile) write 4
    // contiguous 36B runs (one per kq) -> merged to full lines in L2.
    // LeakyReLU as fmaxf(v, 0.1v): identical result, 1 fewer VALU op.
    const float sc = 1.0f / (float)Cn;
    const size_t rowbase = ((size_t)((b * Hh + h0 + wv) * Ww) + w0) * 81;
#pragma unroll
    for (int rg = 0; rg < 4; ++rg) {
        int m = kq * 4 + rg;
        int d = nI - m;
        bool t0 = (d >= 0 && d <= 8);
        bool t1 = (d >= -8 && d <= 0 && nI >= 8);
        size_t mb = rowbase + (size_t)m * 81;
#pragma unroll
        for (int sh = 0; sh < 9; ++sh) {
            if (t0) {
                float v = ac0[sh][rg] * sc;
                out[mb + sh * 9 + d] = fmaxf(v, NEG * v);
            }
            if (t1) {
                float v = ac1[sh][rg] * sc;
                out[mb + sh * 9 + d + 8] = fmaxf(v, NEG * v);
            }
        }
    }
}

extern "C" void kernel_launch(void* const* d_in, const int* in_sizes, int n_in,
                              void* d_out, int out_size, void* d_ws, size_t ws_size,
                              hipStream_t stream) {
    const float* x1 = (const float*)d_in[0];
    const float* wp = (const float*)d_in[1];
    float* out = (float*)d_out;
    dim3 grid(12 * 16 * 8, 1, 1);   // 1536 blocks, XCD-swizzled in-kernel
    costvol_mfma<<<grid, NTHR, 0, stream>>>(x1, wp, out);
}

// Round 17
// 61.713 us; speedup vs baseline: 1.7526x; 1.0024x over previous
//
#include <hip/hip_runtime.h>

// CostVolume via banded-correlation MFMA (v_mfma_f32_16x16x32_f16).
// cost[b,h,w,(sh+4)*9+(sw+4)] = LeakyReLU_0.1( mean_c x1[b,h,w,c]*warped[b,h+sh,w+sw,c] )
// B=8 H=128 W=192 C=128, MD=4. Output fp32 [B,H,W,81].
//
// CHAMPION (R11 structure + fmaxf LeakyReLU). Session 87.2 -> 55.3us.
// R16 drew 61.9us at bench level but profiled dispatches were byte-identical
// to R11/R14 (~93us under rocprof, same FETCH/WRITE/conflicts/VGPR/occ) ->
// bench variance ~12% (clock state), not a code effect. Resubmitted for a
// fresh draw; verified best draws: 55.34 (R11), 55.25 (R14).
//
// Evidence ledger (all measured, this session):
//  - direct band stores replace LDS epilogue (R3, -10us; WRITE == ideal)
//  - rolling x1 prefetch + ro0+128 fold (R4, -18us)
//  - dual-set depth-2 staging prefetch (R11, -4.4us; two 49KB bursts in
//    flight, load->commit >= 1.5-2 steps)
//  - occupancy levers DEAD (R5/R8); depth-3 parking DEAD (R12: allocator
//    pins arch VGPR at 64); LDS conflicts off-critical-path (R14);
//    multi-tile blocks DEAD x2 (R10/R15: band-store line merging needs
//    temporally-compact single-tile store bursts); operand flip DEAD (R7);
//    halo amplification DEAD (R1/R5); setprio hurts lockstep waves (R13);
//    lgkm-vs-full barrier neutral (R2); lb(512,4) LOAD-BEARING (lb3 ->
//    21.6% occupancy cliff).
// Remaining gap to the 27us HBM floor is the phase-serialized decomposition
// itself (64 arch + 72 AGPR shape -> ~1.6 resident blocks, ~50% HBM duty);
// beating it requires a different register-shape design, not perturbation.
//
// Structure: 8x16 tile, 8 waves (wave = one h-row, all 81 shifts).
// Warped staged in LDS [row][kq][px ^ (kq<<1)] 16B slots (conflict-free
// staging writes and B-fragment reads); x1 in registers; K-chunks of 32,
// double-buffered; XCD swizzle (192 wg = one image per XCD); direct band
// stores (36B runs merge to full lines in L2).

namespace {
constexpr int Bb = 8, Hh = 128, Ww = 192, Cn = 128;
constexpr int MDc = 4;
constexpr int TH = 8, TWT = 16;        // block tile: 8 rows x 16 px
constexpr int NTHR = 512;              // 8 waves
constexpr int RH = 16;                 // staged warped rows  (h0-4 .. h0+11)
constexpr int RPX = 24;                // staged warped px    (w0-4 .. w0+19)
constexpr int KC = 32;                 // channels per chunk
constexpr int NCH = Cn / KC;           // 4
constexpr int KQB = RPX * 16;          // 384 B per kq-plane (24 x 16B slots)
constexpr int ROWB = 4 * KQB;          // 1536 B per staged row
constexpr int BUFB = RH * ROWB;        // 24576 B per buffer
constexpr int RUNS = RH * RPX * 4;     // 1536 8-channel runs per chunk
constexpr int NIT = RUNS / NTHR;       // 3
constexpr float NEG = 0.1f;
}

typedef __fp16 h2v   __attribute__((ext_vector_type(2)));
typedef __fp16 f16x8 __attribute__((ext_vector_type(8)));
typedef float  f32x4 __attribute__((ext_vector_type(4)));

__device__ __forceinline__ unsigned pkh2(float a, float b) {
    h2v h = __builtin_amdgcn_cvt_pkrtz(a, b);
    return __builtin_bit_cast(unsigned, h);
}

// Barrier with LDS-only drain: global prefetch loads stay in flight across it.
__device__ __forceinline__ void barrier_lgkm() {
    asm volatile("s_waitcnt lgkmcnt(0)\n\ts_barrier" ::: "memory");
}

__global__ __launch_bounds__(NTHR, 4)
void costvol_mfma(const float* __restrict__ x1,
                  const float* __restrict__ wp,
                  float* __restrict__ out)
{
    __shared__ __align__(16) unsigned char smem[2 * BUFB];   // 48 KiB

    const int tid  = threadIdx.x;
    const int wv   = tid >> 6;        // 0..7 : h-row within stripe
    const int lane = tid & 63;
    const int nI   = lane & 15;       // A-row m / B-col n lane index
    const int kq   = lane >> 4;       // 0..3 : k-group (8 channels each)

    // XCD swizzle: 1536 wg = 8 XCDs x 192; 192 = one batch image (12x16).
    const int id = blockIdx.x;
    const int wg = (id & 7) * 192 + (id >> 3);
    const int bx = wg % 12;
    const int t2 = wg / 12;
    const int by = t2 & 15;
    const int bz = t2 >> 4;

    const int w0 = bx * TWT;
    const int h0 = by * TH;
    const int b  = bz;

    // ---- warped staging decode: run = (row, px, kq), kq innermost ----
    int g_off[NIT]; int l_off[NIT]; bool g_ok[NIT];
#pragma unroll
    for (int it = 0; it < NIT; ++it) {
        int s   = tid + it * NTHR;    // 0..1535
        int skq = s & 3;
        int t   = s >> 2;             // 0..383
        int px  = t % RPX;
        int row = t / RPX;
        int hw  = h0 - MDc + row;
        int ww  = w0 - MDc + px;
        bool ok = (unsigned)hw < (unsigned)Hh && (unsigned)ww < (unsigned)Ww;
        g_ok[it]  = ok;
        g_off[it] = ((b * Hh + (ok ? hw : 0)) * Ww + (ok ? ww : 0)) * Cn + skq * 8;
        l_off[it] = row * ROWB + skq * KQB + ((px ^ (skq << 1)) * 16);
    }

    // Two independent staging register sets: A = even chunks, B = odd.
    uint4 gpA[NIT], gpB[NIT];
    auto LOADA = [&](int ch) {
#pragma unroll
        for (int it = 0; it < NIT; ++it) {
            if (g_ok[it]) {
                const float* p = wp + g_off[it] + ch * KC;
                float4 u = *reinterpret_cast<const float4*>(p);
                float4 v = *reinterpret_cast<const float4*>(p + 4);
                gpA[it] = make_uint4(pkh2(u.x, u.y), pkh2(u.z, u.w),
                                     pkh2(v.x, v.y), pkh2(v.z, v.w));
            } else {
                gpA[it] = make_uint4(0u, 0u, 0u, 0u);
            }
        }
    };
    auto LOADB = [&](int ch) {
#pragma unroll
        for (int it = 0; it < NIT; ++it) {
            if (g_ok[it]) {
                const float* p = wp + g_off[it] + ch * KC;
                float4 u = *reinterpret_cast<const float4*>(p);
                float4 v = *reinterpret_cast<const float4*>(p + 4);
                gpB[it] = make_uint4(pkh2(u.x, u.y), pkh2(u.z, u.w),
                                     pkh2(v.x, v.y), pkh2(v.z, v.w));
            } else {
                gpB[it] = make_uint4(0u, 0u, 0u, 0u);
            }
        }
    };
    auto WRITEA = [&](int buf) {
#pragma unroll
        for (int it = 0; it < NIT; ++it)
            *reinterpret_cast<uint4*>(smem + buf * BUFB + l_off[it]) = gpA[it];
    };
    auto WRITEB = [&](int buf) {
#pragma unroll
        for (int it = 0; it < NIT; ++it)
            *reinterpret_cast<uint4*>(smem + buf * BUFB + l_off[it]) = gpB[it];
    };

    // ---- prologue: issue c0,c1 back-to-back, then x1, commit c0, issue c2.
    LOADA(0);
    LOADB(1);

    const float* xp = x1 + ((size_t)((b * Hh + h0 + wv) * Ww) + w0 + nI) * Cn + kq * 8;
    float4 ar_u = *reinterpret_cast<const float4*>(xp);
    float4 ar_v = *reinterpret_cast<const float4*>(xp + 4);

    f32x4 ac0[9], ac1[9];
#pragma unroll
    for (int s = 0; s < 9; ++s) {
        f32x4 z = {0.f, 0.f, 0.f, 0.f};
        ac0[s] = z; ac1[s] = z;
    }

    // per-lane B fragment offset within a staged row; tile1 = ro0 + 128
    // (identity: ((nI+8)^(kq<<1))*16 == (nI^(kq<<1))*16 + 128)
    const int ro0 = kq * KQB + ((nI ^ (kq << 1)) * 16);

    WRITEA(0);       // commit c0 -> buf0 (waits only on gpA's loads)
    LOADA(2);        // c2 in flight across steps 0..1

    int cur = 0;
#pragma unroll
    for (int ch = 0; ch < NCH; ++ch) {
        barrier_lgkm();
        // commit chunk ch+1 into the other buffer; issue chunk ch+3
        if (ch == 0) { WRITEB(1); LOADB(3); }   // c1 -> buf1; c3 spans steps 0..2
        if (ch == 1) { WRITEA(0); }             // c2 -> buf0
        if (ch == 2) { WRITEB(1); }             // c3 -> buf1
        // x1: convert this chunk (loaded last step), issue next chunk
        uint4 afr = make_uint4(pkh2(ar_u.x, ar_u.y), pkh2(ar_u.z, ar_u.w),
                               pkh2(ar_v.x, ar_v.y), pkh2(ar_v.z, ar_v.w));
        if (ch + 1 < NCH) {
            ar_u = *reinterpret_cast<const float4*>(xp + (ch + 1) * KC);
            ar_v = *reinterpret_cast<const float4*>(xp + (ch + 1) * KC + 4);
        }
        f16x8 av = __builtin_bit_cast(f16x8, afr);
        const unsigned char* base = smem + cur * BUFB;
#pragma unroll
        for (int sh = 0; sh < 9; ++sh) {
            const unsigned char* rp = base + (wv + sh) * ROWB;   // staged row ly+sh
            uint4 b0 = *reinterpret_cast<const uint4*>(rp + ro0);
            uint4 b1 = *reinterpret_cast<const uint4*>(rp + ro0 + 128);
            ac0[sh] = __builtin_amdgcn_mfma_f32_16x16x32_f16(
                av, __builtin_bit_cast(f16x8, b0), ac0[sh], 0, 0, 0);
            ac1[sh] = __builtin_amdgcn_mfma_f32_16x16x32_f16(
                av, __builtin_bit_cast(f16x8, b1), ac1[sh], 0, 0, 0);
        }
        cur ^= 1;
    }

    // ---- direct band stores: no LDS round-trip, no barriers ----
    // C/D map: col=n=lane&15, row=m=(lane>>4)*4+reg
    // tile0: staged px p = nI      -> (m, sw4 = nI-m),   valid d=nI-m in [0,8]
    // tile1: staged px p = nI + 8  -> (m, sw4 = nI-m+8), valid d in [-8,0] && nI>=8
    // out k-index = sh*9 + sw4. Active lanes per (rg,sh,tile) write 4
    // contiguous 36B runs (one per kq) -> merged to full lines in L2.
    // LeakyReLU as fmaxf(v, 0.1v): identical result, 1 fewer VALU op.
    const float sc = 1.0f / (float)Cn;
    const size_t rowbase = ((size_t)((b * Hh + h0 + wv) * Ww) + w0) * 81;
#pragma unroll
    for (int rg = 0; rg < 4; ++rg) {
        int m = kq * 4 + rg;
        int d = nI - m;
        bool t0 = (d >= 0 && d <= 8);
        bool t1 = (d >= -8 && d <= 0 && nI >= 8);
        size_t mb = rowbase + (size_t)m * 81;
#pragma unroll
        for (int sh = 0; sh < 9; ++sh) {
            if (t0) {
                float v = ac0[sh][rg] * sc;
                out[mb + sh * 9 + d] = fmaxf(v, NEG * v);
            }
            if (t1) {
                float v = ac1[sh][rg] * sc;
                out[mb + sh * 9 + d + 8] = fmaxf(v, NEG * v);
            }
        }
    }
}

extern "C" void kernel_launch(void* const* d_in, const int* in_sizes, int n_in,
                              void* d_out, int out_size, void* d_ws, size_t ws_size,
                              hipStream_t stream) {
    const float* x1 = (const float*)d_in[0];
    const float* wp = (const float*)d_in[1];
    float* out = (float*)d_out;
    dim3 grid(12 * 16 * 8, 1, 1);   // 1536 blocks, XCD-swizzled in-kernel
    costvol_mfma<<<grid, NTHR, 0, stream>>>(x1, wp, out);
}